// Round 1
// baseline (948.044 us; speedup 1.0000x reference)
//
#include <hip/hip_runtime.h>
#include <hip/hip_bf16.h>
#include <math.h>

// Problem constants (from reference setup_inputs)
#define NNODES 100000
#define F_IN   500
#define F_MID  64
#define F_OUT  40

// ---------------------------------------------------------------------------
// CSR build: histogram -> two-level exclusive scan -> fill via atomic cursors
// ---------------------------------------------------------------------------

__global__ void hist_kernel(const int* __restrict__ dst, int* __restrict__ cnt, int E) {
    int e = blockIdx.x * blockDim.x + threadIdx.x;
    if (e < E) atomicAdd(&cnt[dst[e]], 1);
}

// Per-block (1024-wide) local exclusive scan of (cnt[i]+1); block totals to bsum.
__global__ __launch_bounds__(1024) void scan_local(const int* __restrict__ cnt,
                                                   int* __restrict__ row_start,
                                                   int* __restrict__ bsum, int n) {
    __shared__ int wsum[16];
    int t = threadIdx.x;
    int i = blockIdx.x * 1024 + t;
    int lane = t & 63, w = t >> 6;
    int v = (i < n) ? (cnt[i] + 1) : 0;
    int s = v;
#pragma unroll
    for (int off = 1; off < 64; off <<= 1) {
        int u = __shfl_up(s, off, 64);
        if (lane >= off) s += u;
    }
    if (lane == 63) wsum[w] = s;
    __syncthreads();
    if (w == 0) {
        int ws = (lane < 16) ? wsum[lane] : 0;
#pragma unroll
        for (int off = 1; off < 16; off <<= 1) {
            int u = __shfl_up(ws, off, 64);
            if (lane >= off) ws += u;
        }
        if (lane < 16) wsum[lane] = ws;
    }
    __syncthreads();
    int wexcl = (w > 0) ? wsum[w - 1] : 0;
    int incl = s + wexcl;
    if (i < n) row_start[i] = incl - v;          // local exclusive
    if (t == 1023) bsum[blockIdx.x] = incl;      // block total
}

// Single block scans the (<=128) block sums -> exclusive offsets + grand total.
__global__ void scan_bsum(const int* __restrict__ bsum, int* __restrict__ boff, int nb) {
    __shared__ int wt[2];
    int t = threadIdx.x;            // 128 threads
    int lane = t & 63, w = t >> 6;
    int v = (t < nb) ? bsum[t] : 0;
    int s = v;
#pragma unroll
    for (int off = 1; off < 64; off <<= 1) {
        int u = __shfl_up(s, off, 64);
        if (lane >= off) s += u;
    }
    if (lane == 63) wt[w] = s;
    __syncthreads();
    int incl = s + ((w == 1) ? wt[0] : 0);
    if (t < nb) boff[t] = incl - v;
    if (t == 127) boff[nb] = incl;  // grand total (= E + N)
}

__global__ __launch_bounds__(1024) void scan_apply(const int* __restrict__ cnt,
                                                   int* __restrict__ row_start,
                                                   int* __restrict__ cursor,
                                                   float* __restrict__ dinv,
                                                   const int* __restrict__ boff,
                                                   int n, int nb) {
    int i = blockIdx.x * 1024 + threadIdx.x;
    if (i < n) {
        int v = row_start[i] + boff[blockIdx.x];
        row_start[i] = v;
        cursor[i] = v;
        dinv[i] = rsqrtf((float)(cnt[i] + 1));
    }
    if (i == 0) row_start[n] = boff[nb];
}

// Fill CSR: first E entries are real edges, last NNODES entries are self-loops.
__global__ void fill_kernel(const int* __restrict__ src, const int* __restrict__ dst,
                            int* __restrict__ cursor, int* __restrict__ csr_src,
                            int E, int total) {
    int e = blockIdx.x * blockDim.x + threadIdx.x;
    if (e >= total) return;
    int s, d;
    if (e < E) { s = src[e]; d = dst[e]; }
    else       { s = e - E; d = s; }
    int pos = atomicAdd(&cursor[d], 1);
    csr_src[pos] = s;
}

// ---------------------------------------------------------------------------
// GEMM1: h1s[100000,64] = (X[100000,500] @ W1[500,64]) * dinv[row]
// 64x64 tile, BK=50 (500 = 10*50), 256 threads, 4x4 register tile.
// ---------------------------------------------------------------------------
__global__ __launch_bounds__(256) void gemm1_kernel(const float* __restrict__ X,
                                                    const float* __restrict__ W,
                                                    const float* __restrict__ dinv,
                                                    float* __restrict__ h1s) {
    const int BM = 64, BK = 50;
    __shared__ __align__(16) float Xs[BK][BM + 4];  // [k][row], stride 68 floats
    __shared__ __align__(16) float Ws[BK][F_MID];   // [k][col]

    int tid = threadIdx.x;
    int block_row = blockIdx.x * BM;
    int rg = tid >> 4;              // 0..15
    int cg = tid & 15;              // 0..15
    int r0 = rg * 4, c0 = cg * 4;

    float acc[4][4] = {};

    for (int k0 = 0; k0 < F_IN; k0 += BK) {
        // stage X tile (transposed into [k][row])
        for (int idx = tid; idx < BM * BK; idx += 256) {
            int r = idx / BK;
            int k = idx - r * BK;
            int gr = block_row + r;
            if (gr >= NNODES) gr = NNODES - 1;
            Xs[k][r] = X[(size_t)gr * F_IN + k0 + k];
        }
        // stage W tile
        for (int idx = tid; idx < BK * F_MID; idx += 256) {
            int k = idx >> 6;
            int c = idx & 63;
            Ws[k][c] = W[(k0 + k) * F_MID + c];
        }
        __syncthreads();
#pragma unroll 2
        for (int kk = 0; kk < BK; kk++) {
            float4 wv = *(const float4*)&Ws[kk][c0];
            float4 xv = *(const float4*)&Xs[kk][r0];
            float xr[4] = {xv.x, xv.y, xv.z, xv.w};
            float wc[4] = {wv.x, wv.y, wv.z, wv.w};
#pragma unroll
            for (int j = 0; j < 4; j++)
#pragma unroll
                for (int i = 0; i < 4; i++)
                    acc[j][i] = fmaf(xr[j], wc[i], acc[j][i]);
        }
        __syncthreads();
    }

#pragma unroll
    for (int j = 0; j < 4; j++) {
        int gr = block_row + r0 + j;
        if (gr < NNODES) {
            float sc = dinv[gr];
            float4 o;
            o.x = acc[j][0] * sc; o.y = acc[j][1] * sc;
            o.z = acc[j][2] * sc; o.w = acc[j][3] * sc;
            *(float4*)&h1s[(size_t)gr * F_MID + c0] = o;
        }
    }
}

// ---------------------------------------------------------------------------
// agg1: one wave per node; lane = feature (64). out1 = relu(dinv*sum + b1)
// ---------------------------------------------------------------------------
__global__ __launch_bounds__(64) void agg1_kernel(const float* __restrict__ h1s,
                                                  const int* __restrict__ csr_src,
                                                  const int* __restrict__ row_start,
                                                  const float* __restrict__ dinv,
                                                  const float* __restrict__ b1,
                                                  float* __restrict__ out1) {
    int node = blockIdx.x;
    int lane = threadIdx.x;
    int s0 = row_start[node], s1 = row_start[node + 1];
    float acc = 0.f;
    int e = s0;
    int sA = (e < s1) ? csr_src[e] : 0;
    for (; e < s1; e++) {
        int sB = (e + 1 < s1) ? csr_src[e + 1] : 0;   // prefetch next index
        acc += h1s[(size_t)sA * F_MID + lane];
        sA = sB;
    }
    float v = acc * dinv[node] + b1[lane];
    out1[(size_t)node * F_MID + lane] = fmaxf(v, 0.f);
}

// ---------------------------------------------------------------------------
// GEMM2: h2s[100000,40] = (out1[100000,64] @ W2[64,40]) * dinv[row]
// one wave per row; row held across lanes, broadcast via shfl.
// ---------------------------------------------------------------------------
__global__ __launch_bounds__(64) void gemm2_kernel(const float* __restrict__ out1,
                                                   const float* __restrict__ W2,
                                                   const float* __restrict__ dinv,
                                                   float* __restrict__ h2s) {
    int node = blockIdx.x;
    int lane = threadIdx.x;
    float x = out1[(size_t)node * F_MID + lane];
    int cl = (lane < F_OUT) ? lane : (F_OUT - 1);
    float acc = 0.f;
#pragma unroll 8
    for (int k = 0; k < F_MID; k++) {
        float xv = __shfl(x, k, 64);
        acc = fmaf(xv, W2[k * F_OUT + cl], acc);
    }
    if (lane < F_OUT) h2s[(size_t)node * F_OUT + lane] = acc * dinv[node];
}

// ---------------------------------------------------------------------------
// agg2 + bias + log_softmax fused: one wave per node, lanes 0..39 = classes.
// ---------------------------------------------------------------------------
__global__ __launch_bounds__(64) void agg2_softmax_kernel(const float* __restrict__ h2s,
                                                          const int* __restrict__ csr_src,
                                                          const int* __restrict__ row_start,
                                                          const float* __restrict__ dinv,
                                                          const float* __restrict__ b2,
                                                          float* __restrict__ out) {
    int node = blockIdx.x;
    int lane = threadIdx.x;
    int cl = (lane < F_OUT) ? lane : 0;
    int s0 = row_start[node], s1 = row_start[node + 1];
    float acc = 0.f;
    int e = s0;
    int sA = (e < s1) ? csr_src[e] : 0;
    for (; e < s1; e++) {
        int sB = (e + 1 < s1) ? csr_src[e + 1] : 0;
        acc += h2s[(size_t)sA * F_OUT + cl];
        sA = sB;
    }
    float z = acc * dinv[node] + b2[cl];
    float zm = (lane < F_OUT) ? z : -3.4e38f;
#pragma unroll
    for (int off = 32; off; off >>= 1) zm = fmaxf(zm, __shfl_xor(zm, off, 64));
    float p = (lane < F_OUT) ? __expf(z - zm) : 0.f;
    float ps = p;
#pragma unroll
    for (int off = 32; off; off >>= 1) ps += __shfl_xor(ps, off, 64);
    float res = z - zm - logf(ps);
    if (lane < F_OUT) out[(size_t)node * F_OUT + lane] = res;
}

// ---------------------------------------------------------------------------
extern "C" void kernel_launch(void* const* d_in, const int* in_sizes, int n_in,
                              void* d_out, int out_size, void* d_ws, size_t ws_size,
                              hipStream_t stream) {
    const float* X   = (const float*)d_in[0];
    const int*   ei  = (const int*)d_in[1];
    const float* W1  = (const float*)d_in[2];
    const float* b1  = (const float*)d_in[3];
    const float* W2  = (const float*)d_in[4];
    const float* b2  = (const float*)d_in[5];
    float* out = (float*)d_out;

    const int N = NNODES;
    const int E = in_sizes[1] / 2;      // 1,600,000
    const int TOTAL = E + N;            // CSR entries incl. self-loops
    const int* srcv = ei;
    const int* dstv = ei + E;

    // ---- workspace carve (256B aligned) ----
    char* p = (char*)d_ws;
    auto carve = [&](size_t bytes) {
        void* r = (void*)p;
        p += (bytes + 255) & ~(size_t)255;
        return r;
    };
    int*   cnt       = (int*)carve((size_t)N * 4);
    int*   row_start = (int*)carve((size_t)(N + 1) * 4);
    int*   cursor    = (int*)carve((size_t)N * 4);
    int*   bsum      = (int*)carve(512);
    int*   boff      = (int*)carve(512 + 4);
    int*   csr_src   = (int*)carve((size_t)TOTAL * 4);
    float* dinv      = (float*)carve((size_t)N * 4);
    float* h1s       = (float*)carve((size_t)N * F_MID * 4);
    float* out1      = (float*)carve((size_t)N * F_MID * 4);
    float* h2s       = (float*)carve((size_t)N * F_OUT * 4);
    (void)ws_size; (void)n_in; (void)out_size;

    const int nb = (N + 1023) / 1024;   // 98 scan blocks

    hipMemsetAsync(cnt, 0, (size_t)N * 4, stream);
    hist_kernel<<<(E + 255) / 256, 256, 0, stream>>>(dstv, cnt, E);
    scan_local<<<nb, 1024, 0, stream>>>(cnt, row_start, bsum, N);
    scan_bsum<<<1, 128, 0, stream>>>(bsum, boff, nb);
    scan_apply<<<nb, 1024, 0, stream>>>(cnt, row_start, cursor, dinv, boff, N, nb);
    fill_kernel<<<(TOTAL + 255) / 256, 256, 0, stream>>>(srcv, dstv, cursor, csr_src, E, TOTAL);

    gemm1_kernel<<<(N + 63) / 64, 256, 0, stream>>>(X, W1, dinv, h1s);
    agg1_kernel<<<N, 64, 0, stream>>>(h1s, csr_src, row_start, dinv, b1, out1);
    gemm2_kernel<<<N, 64, 0, stream>>>(out1, W2, dinv, h2s);
    agg2_softmax_kernel<<<N, 64, 0, stream>>>(h2s, csr_src, row_start, dinv, b2, out);
}

// Round 2
// 899.672 us; speedup vs baseline: 1.0538x; 1.0538x over previous
//
#include <hip/hip_runtime.h>
#include <hip/hip_bf16.h>
#include <math.h>

// Problem constants (from reference setup_inputs)
#define NNODES 100000
#define F_IN   500
#define F_MID  64
#define F_OUT  40
#define KPAD   512     // F_IN padded to multiple of 32 for MFMA

typedef __attribute__((ext_vector_type(8))) short short8;   // 8 bf16 = 4 VGPRs
typedef __attribute__((ext_vector_type(4))) float f32x4;    // MFMA acc

__device__ __forceinline__ unsigned short f2bf(float f) {
    union { float f; unsigned u; } c; c.f = f;
    unsigned r = c.u + 0x7FFF + ((c.u >> 16) & 1);   // round-nearest-even
    return (unsigned short)(r >> 16);
}

// ---------------------------------------------------------------------------
// CSR build: histogram -> two-level exclusive scan -> fill via atomic cursors
// ---------------------------------------------------------------------------

__global__ void hist_kernel(const int* __restrict__ dst, int* __restrict__ cnt, int E) {
    int e = blockIdx.x * blockDim.x + threadIdx.x;
    if (e < E) atomicAdd(&cnt[dst[e]], 1);
}

__global__ __launch_bounds__(1024) void scan_local(const int* __restrict__ cnt,
                                                   int* __restrict__ row_start,
                                                   int* __restrict__ bsum, int n) {
    __shared__ int wsum[16];
    int t = threadIdx.x;
    int i = blockIdx.x * 1024 + t;
    int lane = t & 63, w = t >> 6;
    int v = (i < n) ? (cnt[i] + 1) : 0;
    int s = v;
#pragma unroll
    for (int off = 1; off < 64; off <<= 1) {
        int u = __shfl_up(s, off, 64);
        if (lane >= off) s += u;
    }
    if (lane == 63) wsum[w] = s;
    __syncthreads();
    if (w == 0) {
        int ws = (lane < 16) ? wsum[lane] : 0;
#pragma unroll
        for (int off = 1; off < 16; off <<= 1) {
            int u = __shfl_up(ws, off, 64);
            if (lane >= off) ws += u;
        }
        if (lane < 16) wsum[lane] = ws;
    }
    __syncthreads();
    int wexcl = (w > 0) ? wsum[w - 1] : 0;
    int incl = s + wexcl;
    if (i < n) row_start[i] = incl - v;
    if (t == 1023) bsum[blockIdx.x] = incl;
}

__global__ void scan_bsum(const int* __restrict__ bsum, int* __restrict__ boff, int nb) {
    __shared__ int wt[2];
    int t = threadIdx.x;            // 128 threads
    int lane = t & 63, w = t >> 6;
    int v = (t < nb) ? bsum[t] : 0;
    int s = v;
#pragma unroll
    for (int off = 1; off < 64; off <<= 1) {
        int u = __shfl_up(s, off, 64);
        if (lane >= off) s += u;
    }
    if (lane == 63) wt[w] = s;
    __syncthreads();
    int incl = s + ((w == 1) ? wt[0] : 0);
    if (t < nb) boff[t] = incl - v;
    if (t == 127) boff[nb] = incl;
}

__global__ __launch_bounds__(1024) void scan_apply(const int* __restrict__ cnt,
                                                   int* __restrict__ row_start,
                                                   int* __restrict__ cursor,
                                                   float* __restrict__ dinv,
                                                   const int* __restrict__ boff,
                                                   int n, int nb) {
    int i = blockIdx.x * 1024 + threadIdx.x;
    if (i < n) {
        int v = row_start[i] + boff[blockIdx.x];
        row_start[i] = v;
        cursor[i] = v;
        dinv[i] = rsqrtf((float)(cnt[i] + 1));
    }
    if (i == 0) row_start[n] = boff[nb];
}

__global__ void fill_kernel(const int* __restrict__ src, const int* __restrict__ dst,
                            int* __restrict__ cursor, int* __restrict__ csr_src,
                            int E, int total) {
    int e = blockIdx.x * blockDim.x + threadIdx.x;
    if (e >= total) return;
    int s, d;
    if (e < E) { s = src[e]; d = dst[e]; }
    else       { s = e - E; d = s; }
    int pos = atomicAdd(&cursor[d], 1);
    csr_src[pos] = s;
}

// ---------------------------------------------------------------------------
// W1 -> bf16, transposed, K padded: W1T[n][k], n<64, k<512
// ---------------------------------------------------------------------------
__global__ void w1t_prep(const float* __restrict__ W1, unsigned short* __restrict__ W1T) {
    int idx = blockIdx.x * blockDim.x + threadIdx.x;   // 64*512
    if (idx >= F_MID * KPAD) return;
    int n = idx >> 9;          // /512
    int k = idx & (KPAD - 1);
    float v = (k < F_IN) ? W1[k * F_MID + n] : 0.f;
    W1T[idx] = f2bf(v);
}

// ---------------------------------------------------------------------------
// GEMM1 (bf16 MFMA): h1s[100000,64] = (X @ W1) * dinv[row]
// BM=128, BN=64, BK=32. 256 threads = 4 waves; wave handles 32 rows x 64 cols
// as 2x4 tiles of 16x16, mfma_f32_16x16x32_bf16, fp32 accumulate.
// ---------------------------------------------------------------------------
__global__ __launch_bounds__(256) void gemm1_kernel(const float* __restrict__ X,
                                                    const unsigned short* __restrict__ W1T,
                                                    const float* __restrict__ dinv,
                                                    float* __restrict__ h1s) {
    const int BM = 128, BK = 32;
    __shared__ __align__(16) unsigned short A_lds[BM][BK];   // 8 KB
    __shared__ __align__(16) unsigned short B_lds[F_MID][BK]; // 4 KB

    int tid  = threadIdx.x;
    int wave = tid >> 6;
    int lane = tid & 63;
    int block_row = blockIdx.x * BM;

    // staging map: A: row = tid>>1 (0..127), half = tid&1 covers k 16*h..16*h+15
    int ar = tid >> 1, ah = tid & 1;
    int agr = block_row + ar;
    if (agr >= NNODES) agr = NNODES - 1;          // clamp (dup row, stores guarded)
    const float* xrow = X + (size_t)agr * F_IN;
    // B: n = tid>>2 (0..63), chunk = tid&3 covers k 8*c..8*c+7
    int bn = tid >> 2, bc = tid & 3;

    int mcol = lane & 15, quad = lane >> 4;

    f32x4 acc[2][4];
#pragma unroll
    for (int t = 0; t < 2; t++)
#pragma unroll
        for (int c = 0; c < 4; c++) {
            f32x4 z = {0.f, 0.f, 0.f, 0.f};
            acc[t][c] = z;
        }

    // prefetch registers for tile ks
    float4 apf[4];
    uint4  bpf;
    auto load_tile = [&](int ks) {
#pragma unroll
        for (int i = 0; i < 4; i++) {
            int kg = ks * BK + ah * 16 + i * 4;
            if (kg < F_IN) apf[i] = *(const float4*)(xrow + kg);
            else           apf[i] = make_float4(0.f, 0.f, 0.f, 0.f);
        }
        bpf = *(const uint4*)(W1T + (size_t)bn * KPAD + ks * BK + bc * 8);
    };

    load_tile(0);

    const int NK = KPAD / BK;   // 16
    for (int ks = 0; ks < NK; ks++) {
        // regs -> LDS
        unsigned pk[8];
#pragma unroll
        for (int i = 0; i < 4; i++) {
            pk[2 * i]     = (unsigned)f2bf(apf[i].x) | ((unsigned)f2bf(apf[i].y) << 16);
            pk[2 * i + 1] = (unsigned)f2bf(apf[i].z) | ((unsigned)f2bf(apf[i].w) << 16);
        }
        *(uint4*)&A_lds[ar][ah * 16]     = make_uint4(pk[0], pk[1], pk[2], pk[3]);
        *(uint4*)&A_lds[ar][ah * 16 + 8] = make_uint4(pk[4], pk[5], pk[6], pk[7]);
        *(uint4*)&B_lds[bn][bc * 8] = bpf;
        __syncthreads();

        if (ks + 1 < NK) load_tile(ks + 1);   // overlap next global loads with MFMA

        short8 a0 = *(const short8*)&A_lds[wave * 32 + mcol][quad * 8];
        short8 a1 = *(const short8*)&A_lds[wave * 32 + 16 + mcol][quad * 8];
        short8 bf[4];
#pragma unroll
        for (int c = 0; c < 4; c++)
            bf[c] = *(const short8*)&B_lds[c * 16 + mcol][quad * 8];

#pragma unroll
        for (int c = 0; c < 4; c++) {
            acc[0][c] = __builtin_amdgcn_mfma_f32_16x16x32_bf16(a0, bf[c], acc[0][c], 0, 0, 0);
            acc[1][c] = __builtin_amdgcn_mfma_f32_16x16x32_bf16(a1, bf[c], acc[1][c], 0, 0, 0);
        }
        __syncthreads();
    }

    // epilogue: D col = c*16 + (lane&15), row = wave*32 + t*16 + quad*4 + reg
#pragma unroll
    for (int t = 0; t < 2; t++)
#pragma unroll
        for (int reg = 0; reg < 4; reg++) {
            int gr = block_row + wave * 32 + t * 16 + quad * 4 + reg;
            if (gr < NNODES) {
                float sc = dinv[gr];
#pragma unroll
                for (int c = 0; c < 4; c++)
                    h1s[(size_t)gr * F_MID + c * 16 + mcol] = acc[t][c][reg] * sc;
            }
        }
}

// ---------------------------------------------------------------------------
// Fused agg1 + gemm2: 4 nodes per 256-thread block (1 wave per node).
// v = relu(dinv*sum_csr(h1s) + b1)  (lane = feature)
// h2s[node][c] = (v @ W2)[c] * dinv[node]   via shfl-broadcast over k
// ---------------------------------------------------------------------------
__global__ __launch_bounds__(256) void agg1_gemm2_kernel(const float* __restrict__ h1s,
                                                         const int* __restrict__ csr_src,
                                                         const int* __restrict__ row_start,
                                                         const float* __restrict__ dinv,
                                                         const float* __restrict__ b1,
                                                         const float* __restrict__ W2,
                                                         float* __restrict__ h2s) {
    __shared__ float W2s[F_MID * F_OUT];   // 10 KB
    int tid = threadIdx.x;
    for (int i = tid; i < F_MID * F_OUT; i += 256) W2s[i] = W2[i];
    __syncthreads();

    int node = blockIdx.x * 4 + (tid >> 6);
    int lane = tid & 63;
    int s0 = row_start[node], s1 = row_start[node + 1];
    float acc = 0.f;
    int e = s0;
    int sA = (e < s1) ? csr_src[e] : 0;
    for (; e < s1; e++) {
        int sB = (e + 1 < s1) ? csr_src[e + 1] : 0;
        acc += h1s[(size_t)sA * F_MID + lane];
        sA = sB;
    }
    float dn = dinv[node];
    float v = fmaxf(acc * dn + b1[lane], 0.f);

    int cl = (lane < F_OUT) ? lane : 0;
    float o = 0.f;
#pragma unroll 8
    for (int k = 0; k < F_MID; k++) {
        float xv = __shfl(v, k, 64);
        o = fmaf(xv, W2s[k * F_OUT + cl], o);
    }
    if (lane < F_OUT) h2s[(size_t)node * F_OUT + lane] = o * dn;
}

// ---------------------------------------------------------------------------
// agg2 + bias + log_softmax fused: 4 nodes per 256-thread block.
// ---------------------------------------------------------------------------
__global__ __launch_bounds__(256) void agg2_softmax_kernel(const float* __restrict__ h2s,
                                                           const int* __restrict__ csr_src,
                                                           const int* __restrict__ row_start,
                                                           const float* __restrict__ dinv,
                                                           const float* __restrict__ b2,
                                                           float* __restrict__ out) {
    int tid = threadIdx.x;
    int node = blockIdx.x * 4 + (tid >> 6);
    int lane = tid & 63;
    int cl = (lane < F_OUT) ? lane : 0;
    int s0 = row_start[node], s1 = row_start[node + 1];
    float acc = 0.f;
    int e = s0;
    int sA = (e < s1) ? csr_src[e] : 0;
    for (; e < s1; e++) {
        int sB = (e + 1 < s1) ? csr_src[e + 1] : 0;
        acc += h2s[(size_t)sA * F_OUT + cl];
        sA = sB;
    }
    float z = acc * dinv[node] + b2[cl];
    float zm = (lane < F_OUT) ? z : -3.4e38f;
#pragma unroll
    for (int off = 32; off; off >>= 1) zm = fmaxf(zm, __shfl_xor(zm, off, 64));
    float p = (lane < F_OUT) ? __expf(z - zm) : 0.f;
    float ps = p;
#pragma unroll
    for (int off = 32; off; off >>= 1) ps += __shfl_xor(ps, off, 64);
    float res = z - zm - logf(ps);
    if (lane < F_OUT) out[(size_t)node * F_OUT + lane] = res;
}

// ---------------------------------------------------------------------------
extern "C" void kernel_launch(void* const* d_in, const int* in_sizes, int n_in,
                              void* d_out, int out_size, void* d_ws, size_t ws_size,
                              hipStream_t stream) {
    const float* X   = (const float*)d_in[0];
    const int*   ei  = (const int*)d_in[1];
    const float* W1  = (const float*)d_in[2];
    const float* b1  = (const float*)d_in[3];
    const float* W2  = (const float*)d_in[4];
    const float* b2  = (const float*)d_in[5];
    float* out = (float*)d_out;

    const int N = NNODES;
    const int E = in_sizes[1] / 2;      // 1,600,000
    const int TOTAL = E + N;
    const int* srcv = ei;
    const int* dstv = ei + E;

    char* p = (char*)d_ws;
    auto carve = [&](size_t bytes) {
        void* r = (void*)p;
        p += (bytes + 255) & ~(size_t)255;
        return r;
    };
    int*   cnt       = (int*)carve((size_t)N * 4);
    int*   row_start = (int*)carve((size_t)(N + 1) * 4);
    int*   cursor    = (int*)carve((size_t)N * 4);
    int*   bsum      = (int*)carve(512);
    int*   boff      = (int*)carve(512 + 4);
    int*   csr_src   = (int*)carve((size_t)TOTAL * 4);
    float* dinv      = (float*)carve((size_t)N * 4);
    unsigned short* W1T = (unsigned short*)carve((size_t)F_MID * KPAD * 2);
    float* h1s       = (float*)carve((size_t)N * F_MID * 4);
    float* h2s       = (float*)carve((size_t)N * F_OUT * 4);
    (void)ws_size; (void)n_in; (void)out_size;

    const int nb = (N + 1023) / 1024;   // 98

    hipMemsetAsync(cnt, 0, (size_t)N * 4, stream);
    hist_kernel<<<(E + 255) / 256, 256, 0, stream>>>(dstv, cnt, E);
    scan_local<<<nb, 1024, 0, stream>>>(cnt, row_start, bsum, N);
    scan_bsum<<<1, 128, 0, stream>>>(bsum, boff, nb);
    scan_apply<<<nb, 1024, 0, stream>>>(cnt, row_start, cursor, dinv, boff, N, nb);
    fill_kernel<<<(TOTAL + 255) / 256, 256, 0, stream>>>(srcv, dstv, cursor, csr_src, E, TOTAL);
    w1t_prep<<<(F_MID * KPAD + 255) / 256, 256, 0, stream>>>(W1, W1T);

    gemm1_kernel<<<(N + 127) / 128, 256, 0, stream>>>(X, W1T, dinv, h1s);
    agg1_gemm2_kernel<<<N / 4, 256, 0, stream>>>(h1s, csr_src, row_start, dinv, b1, W2, h2s);
    agg2_softmax_kernel<<<N / 4, 256, 0, stream>>>(h2s, csr_src, row_start, dinv, b2, out);
}

// Round 3
// 736.689 us; speedup vs baseline: 1.2869x; 1.2212x over previous
//
#include <hip/hip_runtime.h>
#include <hip/hip_bf16.h>
#include <math.h>

// Problem constants (from reference setup_inputs)
#define NNODES 100000
#define F_IN   500
#define F_MID  64
#define F_OUT  40
#define KPAD   512     // F_IN padded to multiple of 32 for MFMA

typedef __attribute__((ext_vector_type(8))) short short8;   // 8 bf16 = 4 VGPRs
typedef __attribute__((ext_vector_type(4))) float f32x4;    // MFMA acc

__device__ __forceinline__ unsigned short f2bf(float f) {
    union { float f; unsigned u; } c; c.f = f;
    unsigned r = c.u + 0x7FFF + ((c.u >> 16) & 1);   // round-nearest-even
    return (unsigned short)(r >> 16);
}

// ---------------------------------------------------------------------------
// CSR build: histogram -> two-level exclusive scan -> fill via atomic cursors
// ---------------------------------------------------------------------------

__global__ void hist_kernel(const int* __restrict__ dst, int* __restrict__ cnt, int E) {
    int e = blockIdx.x * blockDim.x + threadIdx.x;
    if (e < E) atomicAdd(&cnt[dst[e]], 1);
}

__global__ __launch_bounds__(1024) void scan_local(const int* __restrict__ cnt,
                                                   int* __restrict__ row_start,
                                                   int* __restrict__ bsum, int n) {
    __shared__ int wsum[16];
    int t = threadIdx.x;
    int i = blockIdx.x * 1024 + t;
    int lane = t & 63, w = t >> 6;
    int v = (i < n) ? (cnt[i] + 1) : 0;
    int s = v;
#pragma unroll
    for (int off = 1; off < 64; off <<= 1) {
        int u = __shfl_up(s, off, 64);
        if (lane >= off) s += u;
    }
    if (lane == 63) wsum[w] = s;
    __syncthreads();
    if (w == 0) {
        int ws = (lane < 16) ? wsum[lane] : 0;
#pragma unroll
        for (int off = 1; off < 16; off <<= 1) {
            int u = __shfl_up(ws, off, 64);
            if (lane >= off) ws += u;
        }
        if (lane < 16) wsum[lane] = ws;
    }
    __syncthreads();
    int wexcl = (w > 0) ? wsum[w - 1] : 0;
    int incl = s + wexcl;
    if (i < n) row_start[i] = incl - v;
    if (t == 1023) bsum[blockIdx.x] = incl;
}

__global__ void scan_bsum(const int* __restrict__ bsum, int* __restrict__ boff, int nb) {
    __shared__ int wt[2];
    int t = threadIdx.x;            // 128 threads
    int lane = t & 63, w = t >> 6;
    int v = (t < nb) ? bsum[t] : 0;
    int s = v;
#pragma unroll
    for (int off = 1; off < 64; off <<= 1) {
        int u = __shfl_up(s, off, 64);
        if (lane >= off) s += u;
    }
    if (lane == 63) wt[w] = s;
    __syncthreads();
    int incl = s + ((w == 1) ? wt[0] : 0);
    if (t < nb) boff[t] = incl - v;
    if (t == 127) boff[nb] = incl;
}

__global__ __launch_bounds__(1024) void scan_apply(const int* __restrict__ cnt,
                                                   int* __restrict__ row_start,
                                                   int* __restrict__ cursor,
                                                   float* __restrict__ dinv,
                                                   const int* __restrict__ boff,
                                                   int n, int nb) {
    int i = blockIdx.x * 1024 + threadIdx.x;
    if (i < n) {
        int v = row_start[i] + boff[blockIdx.x];
        row_start[i] = v;
        cursor[i] = v;
        dinv[i] = rsqrtf((float)(cnt[i] + 1));
    }
    if (i == 0) row_start[n] = boff[nb];
}

__global__ void fill_kernel(const int* __restrict__ src, const int* __restrict__ dst,
                            int* __restrict__ cursor, int* __restrict__ csr_src,
                            int E, int total) {
    int e = blockIdx.x * blockDim.x + threadIdx.x;
    if (e >= total) return;
    int s, d;
    if (e < E) { s = src[e]; d = dst[e]; }
    else       { s = e - E; d = s; }
    int pos = atomicAdd(&cursor[d], 1);
    csr_src[pos] = s;
}

// ---------------------------------------------------------------------------
// W1 -> bf16, transposed, K padded: W1T[n][k], n<64, k<512
// ---------------------------------------------------------------------------
__global__ void w1t_prep(const float* __restrict__ W1, unsigned short* __restrict__ W1T) {
    int idx = blockIdx.x * blockDim.x + threadIdx.x;   // 64*512
    if (idx >= F_MID * KPAD) return;
    int n = idx >> 9;          // /512
    int k = idx & (KPAD - 1);
    float v = (k < F_IN) ? W1[k * F_MID + n] : 0.f;
    W1T[idx] = f2bf(v);
}

// ---------------------------------------------------------------------------
// GEMM1 (bf16 MFMA): h1s[100000,64] = (X @ W1) * dinv[row]
// BM=128, BN=64, BK=32. 256 threads = 4 waves; wave handles 32 rows x 64 cols
// as 2x4 tiles of 16x16, mfma_f32_16x16x32_bf16, fp32 accumulate.
// ---------------------------------------------------------------------------
__global__ __launch_bounds__(256) void gemm1_kernel(const float* __restrict__ X,
                                                    const unsigned short* __restrict__ W1T,
                                                    const float* __restrict__ dinv,
                                                    float* __restrict__ h1s) {
    const int BM = 128, BK = 32;
    __shared__ __align__(16) unsigned short A_lds[BM][BK];   // 8 KB
    __shared__ __align__(16) unsigned short B_lds[F_MID][BK]; // 4 KB

    int tid  = threadIdx.x;
    int wave = tid >> 6;
    int lane = tid & 63;
    int block_row = blockIdx.x * BM;

    int ar = tid >> 1, ah = tid & 1;
    int agr = block_row + ar;
    if (agr >= NNODES) agr = NNODES - 1;          // clamp (dup row, stores guarded)
    const float* xrow = X + (size_t)agr * F_IN;
    int bn = tid >> 2, bc = tid & 3;

    int mcol = lane & 15, quad = lane >> 4;

    f32x4 acc[2][4];
#pragma unroll
    for (int t = 0; t < 2; t++)
#pragma unroll
        for (int c = 0; c < 4; c++) {
            f32x4 z = {0.f, 0.f, 0.f, 0.f};
            acc[t][c] = z;
        }

    float4 apf[4];
    uint4  bpf;
    auto load_tile = [&](int ks) {
#pragma unroll
        for (int i = 0; i < 4; i++) {
            int kg = ks * BK + ah * 16 + i * 4;
            if (kg < F_IN) apf[i] = *(const float4*)(xrow + kg);
            else           apf[i] = make_float4(0.f, 0.f, 0.f, 0.f);
        }
        bpf = *(const uint4*)(W1T + (size_t)bn * KPAD + ks * BK + bc * 8);
    };

    load_tile(0);

    const int NK = KPAD / BK;   // 16
    for (int ks = 0; ks < NK; ks++) {
        unsigned pk[8];
#pragma unroll
        for (int i = 0; i < 4; i++) {
            pk[2 * i]     = (unsigned)f2bf(apf[i].x) | ((unsigned)f2bf(apf[i].y) << 16);
            pk[2 * i + 1] = (unsigned)f2bf(apf[i].z) | ((unsigned)f2bf(apf[i].w) << 16);
        }
        *(uint4*)&A_lds[ar][ah * 16]     = make_uint4(pk[0], pk[1], pk[2], pk[3]);
        *(uint4*)&A_lds[ar][ah * 16 + 8] = make_uint4(pk[4], pk[5], pk[6], pk[7]);
        *(uint4*)&B_lds[bn][bc * 8] = bpf;
        __syncthreads();

        if (ks + 1 < NK) load_tile(ks + 1);

        short8 a0 = *(const short8*)&A_lds[wave * 32 + mcol][quad * 8];
        short8 a1 = *(const short8*)&A_lds[wave * 32 + 16 + mcol][quad * 8];
        short8 bf[4];
#pragma unroll
        for (int c = 0; c < 4; c++)
            bf[c] = *(const short8*)&B_lds[c * 16 + mcol][quad * 8];

#pragma unroll
        for (int c = 0; c < 4; c++) {
            acc[0][c] = __builtin_amdgcn_mfma_f32_16x16x32_bf16(a0, bf[c], acc[0][c], 0, 0, 0);
            acc[1][c] = __builtin_amdgcn_mfma_f32_16x16x32_bf16(a1, bf[c], acc[1][c], 0, 0, 0);
        }
        __syncthreads();
    }

#pragma unroll
    for (int t = 0; t < 2; t++)
#pragma unroll
        for (int reg = 0; reg < 4; reg++) {
            int gr = block_row + wave * 32 + t * 16 + quad * 4 + reg;
            if (gr < NNODES) {
                float sc = dinv[gr];
#pragma unroll
                for (int c = 0; c < 4; c++)
                    h1s[(size_t)gr * F_MID + c * 16 + mcol] = acc[t][c][reg] * sc;
            }
        }
}

// ---------------------------------------------------------------------------
// float4 helpers
// ---------------------------------------------------------------------------
__device__ __forceinline__ float4 f4add(float4 a, float4 b) {
    return make_float4(a.x + b.x, a.y + b.y, a.z + b.z, a.w + b.w);
}
__device__ __forceinline__ float4 f4shflxor(float4 a, int m) {
    return make_float4(__shfl_xor(a.x, m, 64), __shfl_xor(a.y, m, 64),
                       __shfl_xor(a.z, m, 64), __shfl_xor(a.w, m, 64));
}

// ---------------------------------------------------------------------------
// Fused agg1 + gemm2: 4 nodes per 256-thread block (1 wave per node).
// Gather: 4 edges per wave-iteration (16-lane groups x float4), 2-deep unroll
// -> 8 independent 16B loads in flight. Cross-group reduce via shfl_xor.
// Then v = relu(acc*dinv + b1) (float4 per lane, features 4*(lane&15)..+3),
// gemm2 via shfl-broadcast over 16 source lanes.
// ---------------------------------------------------------------------------
__global__ __launch_bounds__(256) void agg1_gemm2_kernel(const float* __restrict__ h1s,
                                                         const int* __restrict__ csr_src,
                                                         const int* __restrict__ row_start,
                                                         const float* __restrict__ dinv,
                                                         const float* __restrict__ b1,
                                                         const float* __restrict__ W2,
                                                         float* __restrict__ h2s) {
    __shared__ float W2s[F_MID * F_OUT];   // 10 KB
    int tid = threadIdx.x;
    for (int i = tid; i < F_MID * F_OUT; i += 256) W2s[i] = W2[i];
    __syncthreads();

    int node = blockIdx.x * 4 + (tid >> 6);
    int lane = tid & 63;
    int g = lane >> 4;          // edge slot 0..3
    int l = lane & 15;          // feature quad 0..15

    int s0 = row_start[node], s1 = row_start[node + 1];
    float4 acc0 = make_float4(0.f, 0.f, 0.f, 0.f);
    float4 acc1 = make_float4(0.f, 0.f, 0.f, 0.f);

    int e = s0 + g;
    for (; e + 4 < s1; e += 8) {
        int sa = csr_src[e];
        int sb = csr_src[e + 4];
        float4 va = *(const float4*)&h1s[(size_t)sa * F_MID + l * 4];
        float4 vb = *(const float4*)&h1s[(size_t)sb * F_MID + l * 4];
        acc0 = f4add(acc0, va);
        acc1 = f4add(acc1, vb);
    }
    if (e < s1) {
        int sa = csr_src[e];
        acc0 = f4add(acc0, *(const float4*)&h1s[(size_t)sa * F_MID + l * 4]);
    }
    float4 acc = f4add(acc0, acc1);
    acc = f4add(acc, f4shflxor(acc, 16));
    acc = f4add(acc, f4shflxor(acc, 32));
    // now every lane's acc holds the full sum for features 4l..4l+3 (replicated over g)

    float dn = dinv[node];
    float4 bv = *(const float4*)&b1[l * 4];
    float4 v4;
    v4.x = fmaxf(acc.x * dn + bv.x, 0.f);
    v4.y = fmaxf(acc.y * dn + bv.y, 0.f);
    v4.z = fmaxf(acc.z * dn + bv.z, 0.f);
    v4.w = fmaxf(acc.w * dn + bv.w, 0.f);

    // gemm2: o[cl] = sum_k v[k] * W2[k][cl]; v[k] lives on lane (k>>2), comp k&3
    int cl = (lane < F_OUT) ? lane : 0;
    float o = 0.f;
#pragma unroll
    for (int kg = 0; kg < 16; kg++) {
        float vx = __shfl(v4.x, kg, 64);
        float vy = __shfl(v4.y, kg, 64);
        float vz = __shfl(v4.z, kg, 64);
        float vw = __shfl(v4.w, kg, 64);
        o = fmaf(vx, W2s[(4 * kg + 0) * F_OUT + cl], o);
        o = fmaf(vy, W2s[(4 * kg + 1) * F_OUT + cl], o);
        o = fmaf(vz, W2s[(4 * kg + 2) * F_OUT + cl], o);
        o = fmaf(vw, W2s[(4 * kg + 3) * F_OUT + cl], o);
    }
    if (lane < F_OUT) h2s[(size_t)node * F_OUT + lane] = o * dn;
}

// ---------------------------------------------------------------------------
// agg2 + bias + log_softmax: 4 nodes/block, 4 edges per wave-iteration
// (16-lane groups; lanes l<10 carry float4 covering classes 4l..4l+3).
// ---------------------------------------------------------------------------
__global__ __launch_bounds__(256) void agg2_softmax_kernel(const float* __restrict__ h2s,
                                                           const int* __restrict__ csr_src,
                                                           const int* __restrict__ row_start,
                                                           const float* __restrict__ dinv,
                                                           const float* __restrict__ b2,
                                                           float* __restrict__ out) {
    int tid = threadIdx.x;
    int node = blockIdx.x * 4 + (tid >> 6);
    int lane = tid & 63;
    int g = lane >> 4;
    int l = lane & 15;
    bool act = (l < 10);        // 10 float4 = 40 classes

    int s0 = row_start[node], s1 = row_start[node + 1];
    float4 acc0 = make_float4(0.f, 0.f, 0.f, 0.f);
    float4 acc1 = make_float4(0.f, 0.f, 0.f, 0.f);

    int e = s0 + g;
    for (; e + 4 < s1; e += 8) {
        int sa = csr_src[e];
        int sb = csr_src[e + 4];
        if (act) {
            acc0 = f4add(acc0, *(const float4*)&h2s[(size_t)sa * F_OUT + l * 4]);
            acc1 = f4add(acc1, *(const float4*)&h2s[(size_t)sb * F_OUT + l * 4]);
        }
    }
    if (e < s1) {
        int sa = csr_src[e];
        if (act) acc0 = f4add(acc0, *(const float4*)&h2s[(size_t)sa * F_OUT + l * 4]);
    }
    float4 acc = f4add(acc0, acc1);
    acc = f4add(acc, f4shflxor(acc, 16));
    acc = f4add(acc, f4shflxor(acc, 32));

    float dn = dinv[node];
    float4 z4 = make_float4(0.f, 0.f, 0.f, 0.f);
    if (act) {
        float4 bv = *(const float4*)&b2[l * 4];
        z4.x = acc.x * dn + bv.x;
        z4.y = acc.y * dn + bv.y;
        z4.z = acc.z * dn + bv.z;
        z4.w = acc.w * dn + bv.w;
    }
    // max over 40 classes: local max4, then xor-reduce within 16-group
    float m = act ? fmaxf(fmaxf(z4.x, z4.y), fmaxf(z4.z, z4.w)) : -3.4e38f;
#pragma unroll
    for (int off = 1; off < 16; off <<= 1) m = fmaxf(m, __shfl_xor(m, off, 64));
    float s = 0.f;
    if (act)
        s = __expf(z4.x - m) + __expf(z4.y - m) + __expf(z4.z - m) + __expf(z4.w - m);
#pragma unroll
    for (int off = 1; off < 16; off <<= 1) s += __shfl_xor(s, off, 64);
    float lse = m + logf(s);
    if (act) {
        float4 r = make_float4(z4.x - lse, z4.y - lse, z4.z - lse, z4.w - lse);
        *(float4*)&out[(size_t)node * F_OUT + l * 4] = r;
    }
}

// ---------------------------------------------------------------------------
extern "C" void kernel_launch(void* const* d_in, const int* in_sizes, int n_in,
                              void* d_out, int out_size, void* d_ws, size_t ws_size,
                              hipStream_t stream) {
    const float* X   = (const float*)d_in[0];
    const int*   ei  = (const int*)d_in[1];
    const float* W1  = (const float*)d_in[2];
    const float* b1  = (const float*)d_in[3];
    const float* W2  = (const float*)d_in[4];
    const float* b2  = (const float*)d_in[5];
    float* out = (float*)d_out;

    const int N = NNODES;
    const int E = in_sizes[1] / 2;      // 1,600,000
    const int TOTAL = E + N;
    const int* srcv = ei;
    const int* dstv = ei + E;

    char* p = (char*)d_ws;
    auto carve = [&](size_t bytes) {
        void* r = (void*)p;
        p += (bytes + 255) & ~(size_t)255;
        return r;
    };
    int*   cnt       = (int*)carve((size_t)N * 4);
    int*   row_start = (int*)carve((size_t)(N + 1) * 4);
    int*   cursor    = (int*)carve((size_t)N * 4);
    int*   bsum      = (int*)carve(512);
    int*   boff      = (int*)carve(512 + 4);
    int*   csr_src   = (int*)carve((size_t)TOTAL * 4);
    float* dinv      = (float*)carve((size_t)N * 4);
    unsigned short* W1T = (unsigned short*)carve((size_t)F_MID * KPAD * 2);
    float* h1s       = (float*)carve((size_t)N * F_MID * 4);
    float* h2s       = (float*)carve((size_t)N * F_OUT * 4);
    (void)ws_size; (void)n_in; (void)out_size;

    const int nb = (N + 1023) / 1024;   // 98

    hipMemsetAsync(cnt, 0, (size_t)N * 4, stream);
    hist_kernel<<<(E + 255) / 256, 256, 0, stream>>>(dstv, cnt, E);
    scan_local<<<nb, 1024, 0, stream>>>(cnt, row_start, bsum, N);
    scan_bsum<<<1, 128, 0, stream>>>(bsum, boff, nb);
    scan_apply<<<nb, 1024, 0, stream>>>(cnt, row_start, cursor, dinv, boff, N, nb);
    fill_kernel<<<(TOTAL + 255) / 256, 256, 0, stream>>>(srcv, dstv, cursor, csr_src, E, TOTAL);
    w1t_prep<<<(F_MID * KPAD + 255) / 256, 256, 0, stream>>>(W1, W1T);

    gemm1_kernel<<<(N + 127) / 128, 256, 0, stream>>>(X, W1T, dinv, h1s);
    agg1_gemm2_kernel<<<N / 4, 256, 0, stream>>>(h1s, csr_src, row_start, dinv, b1, W2, h2s);
    agg2_softmax_kernel<<<N / 4, 256, 0, stream>>>(h2s, csr_src, row_start, dinv, b2, out);
}

// Round 4
// 709.915 us; speedup vs baseline: 1.3354x; 1.0377x over previous
//
#include <hip/hip_runtime.h>
#include <hip/hip_bf16.h>
#include <math.h>

// Problem constants (from reference setup_inputs)
#define NNODES 100000
#define F_IN   500
#define F_MID  64
#define F_OUT  40
#define KPAD   512     // F_IN padded to multiple of 32 for MFMA

typedef __attribute__((ext_vector_type(8))) short short8;   // 8 bf16 = 4 VGPRs
typedef __attribute__((ext_vector_type(4))) float f32x4;    // MFMA acc

__device__ __forceinline__ unsigned short f2bf(float f) {
    union { float f; unsigned u; } c; c.f = f;
    unsigned r = c.u + 0x7FFF + ((c.u >> 16) & 1);   // round-nearest-even
    return (unsigned short)(r >> 16);
}

// ---------------------------------------------------------------------------
// CSR build: histogram -> two-level exclusive scan -> fill via atomic cursors
// ---------------------------------------------------------------------------

__global__ void hist_kernel(const int* __restrict__ dst, int* __restrict__ cnt, int E) {
    int e = blockIdx.x * blockDim.x + threadIdx.x;
    if (e < E) atomicAdd(&cnt[dst[e]], 1);
}

__global__ __launch_bounds__(1024) void scan_local(const int* __restrict__ cnt,
                                                   int* __restrict__ row_start,
                                                   int* __restrict__ bsum, int n) {
    __shared__ int wsum[16];
    int t = threadIdx.x;
    int i = blockIdx.x * 1024 + t;
    int lane = t & 63, w = t >> 6;
    int v = (i < n) ? (cnt[i] + 1) : 0;
    int s = v;
#pragma unroll
    for (int off = 1; off < 64; off <<= 1) {
        int u = __shfl_up(s, off, 64);
        if (lane >= off) s += u;
    }
    if (lane == 63) wsum[w] = s;
    __syncthreads();
    if (w == 0) {
        int ws = (lane < 16) ? wsum[lane] : 0;
#pragma unroll
        for (int off = 1; off < 16; off <<= 1) {
            int u = __shfl_up(ws, off, 64);
            if (lane >= off) ws += u;
        }
        if (lane < 16) wsum[lane] = ws;
    }
    __syncthreads();
    int wexcl = (w > 0) ? wsum[w - 1] : 0;
    int incl = s + wexcl;
    if (i < n) row_start[i] = incl - v;
    if (t == 1023) bsum[blockIdx.x] = incl;
}

__global__ void scan_bsum(const int* __restrict__ bsum, int* __restrict__ boff, int nb) {
    __shared__ int wt[2];
    int t = threadIdx.x;            // 128 threads
    int lane = t & 63, w = t >> 6;
    int v = (t < nb) ? bsum[t] : 0;
    int s = v;
#pragma unroll
    for (int off = 1; off < 64; off <<= 1) {
        int u = __shfl_up(s, off, 64);
        if (lane >= off) s += u;
    }
    if (lane == 63) wt[w] = s;
    __syncthreads();
    int incl = s + ((w == 1) ? wt[0] : 0);
    if (t < nb) boff[t] = incl - v;
    if (t == 127) boff[nb] = incl;
}

__global__ __launch_bounds__(1024) void scan_apply(const int* __restrict__ cnt,
                                                   int* __restrict__ row_start,
                                                   int* __restrict__ cursor,
                                                   float* __restrict__ dinv,
                                                   const int* __restrict__ boff,
                                                   int n, int nb) {
    int i = blockIdx.x * 1024 + threadIdx.x;
    if (i < n) {
        int v = row_start[i] + boff[blockIdx.x];
        row_start[i] = v;
        cursor[i] = v;
        dinv[i] = rsqrtf((float)(cnt[i] + 1));
    }
    if (i == 0) row_start[n] = boff[nb];
}

__global__ void fill_kernel(const int* __restrict__ src, const int* __restrict__ dst,
                            int* __restrict__ cursor, int* __restrict__ csr_src,
                            int E, int total) {
    int e = blockIdx.x * blockDim.x + threadIdx.x;
    if (e >= total) return;
    int s, d;
    if (e < E) { s = src[e]; d = dst[e]; }
    else       { s = e - E; d = s; }
    int pos = atomicAdd(&cursor[d], 1);
    csr_src[pos] = s;
}

// ---------------------------------------------------------------------------
// W1 -> bf16, transposed, K padded: W1T[n][k], n<64, k<512
// ---------------------------------------------------------------------------
__global__ void w1t_prep(const float* __restrict__ W1, unsigned short* __restrict__ W1T) {
    int idx = blockIdx.x * blockDim.x + threadIdx.x;   // 64*512
    if (idx >= F_MID * KPAD) return;
    int n = idx >> 9;          // /512
    int k = idx & (KPAD - 1);
    float v = (k < F_IN) ? W1[k * F_MID + n] : 0.f;
    W1T[idx] = f2bf(v);
}

// ---------------------------------------------------------------------------
// GEMM1 (bf16 MFMA): h1s[100000,64] = (X @ W1) * dinv[row]
// BM=128, BN=64, BK=32. 256 threads = 4 waves; wave handles 32 rows x 64 cols
// as 2x4 tiles of 16x16, mfma_f32_16x16x32_bf16, fp32 accumulate.
// ---------------------------------------------------------------------------
__global__ __launch_bounds__(256) void gemm1_kernel(const float* __restrict__ X,
                                                    const unsigned short* __restrict__ W1T,
                                                    const float* __restrict__ dinv,
                                                    float* __restrict__ h1s) {
    const int BM = 128, BK = 32;
    __shared__ __align__(16) unsigned short A_lds[BM][BK];   // 8 KB
    __shared__ __align__(16) unsigned short B_lds[F_MID][BK]; // 4 KB

    int tid  = threadIdx.x;
    int wave = tid >> 6;
    int lane = tid & 63;
    int block_row = blockIdx.x * BM;

    int ar = tid >> 1, ah = tid & 1;
    int agr = block_row + ar;
    if (agr >= NNODES) agr = NNODES - 1;          // clamp (dup row, stores guarded)
    const float* xrow = X + (size_t)agr * F_IN;
    int bn = tid >> 2, bc = tid & 3;

    int mcol = lane & 15, quad = lane >> 4;

    f32x4 acc[2][4];
#pragma unroll
    for (int t = 0; t < 2; t++)
#pragma unroll
        for (int c = 0; c < 4; c++) {
            f32x4 z = {0.f, 0.f, 0.f, 0.f};
            acc[t][c] = z;
        }

    float4 apf[4];
    uint4  bpf;
    auto load_tile = [&](int ks) {
#pragma unroll
        for (int i = 0; i < 4; i++) {
            int kg = ks * BK + ah * 16 + i * 4;
            if (kg < F_IN) apf[i] = *(const float4*)(xrow + kg);
            else           apf[i] = make_float4(0.f, 0.f, 0.f, 0.f);
        }
        bpf = *(const uint4*)(W1T + (size_t)bn * KPAD + ks * BK + bc * 8);
    };

    load_tile(0);

    const int NK = KPAD / BK;   // 16
    for (int ks = 0; ks < NK; ks++) {
        unsigned pk[8];
#pragma unroll
        for (int i = 0; i < 4; i++) {
            pk[2 * i]     = (unsigned)f2bf(apf[i].x) | ((unsigned)f2bf(apf[i].y) << 16);
            pk[2 * i + 1] = (unsigned)f2bf(apf[i].z) | ((unsigned)f2bf(apf[i].w) << 16);
        }
        *(uint4*)&A_lds[ar][ah * 16]     = make_uint4(pk[0], pk[1], pk[2], pk[3]);
        *(uint4*)&A_lds[ar][ah * 16 + 8] = make_uint4(pk[4], pk[5], pk[6], pk[7]);
        *(uint4*)&B_lds[bn][bc * 8] = bpf;
        __syncthreads();

        if (ks + 1 < NK) load_tile(ks + 1);

        short8 a0 = *(const short8*)&A_lds[wave * 32 + mcol][quad * 8];
        short8 a1 = *(const short8*)&A_lds[wave * 32 + 16 + mcol][quad * 8];
        short8 bf[4];
#pragma unroll
        for (int c = 0; c < 4; c++)
            bf[c] = *(const short8*)&B_lds[c * 16 + mcol][quad * 8];

#pragma unroll
        for (int c = 0; c < 4; c++) {
            acc[0][c] = __builtin_amdgcn_mfma_f32_16x16x32_bf16(a0, bf[c], acc[0][c], 0, 0, 0);
            acc[1][c] = __builtin_amdgcn_mfma_f32_16x16x32_bf16(a1, bf[c], acc[1][c], 0, 0, 0);
        }
        __syncthreads();
    }

#pragma unroll
    for (int t = 0; t < 2; t++)
#pragma unroll
        for (int reg = 0; reg < 4; reg++) {
            int gr = block_row + wave * 32 + t * 16 + quad * 4 + reg;
            if (gr < NNODES) {
                float sc = dinv[gr];
#pragma unroll
                for (int c = 0; c < 4; c++)
                    h1s[(size_t)gr * F_MID + c * 16 + mcol] = acc[t][c][reg] * sc;
            }
        }
}

// ---------------------------------------------------------------------------
// float4 helpers
// ---------------------------------------------------------------------------
__device__ __forceinline__ float4 f4add(float4 a, float4 b) {
    return make_float4(a.x + b.x, a.y + b.y, a.z + b.z, a.w + b.w);
}
__device__ __forceinline__ float4 f4shflxor(float4 a, int m) {
    return make_float4(__shfl_xor(a.x, m, 64), __shfl_xor(a.y, m, 64),
                       __shfl_xor(a.z, m, 64), __shfl_xor(a.w, m, 64));
}

// ---------------------------------------------------------------------------
// Fused agg1 + gemm2: 4 nodes per 256-thread block (1 wave per node).
// Index preload: lane i loads csr_src[s0+i] (one coalesced load per 64 edges),
// broadcast via shfl. Each 16-lane group issues 4 independent row-gathers per
// iteration into 4 separate accumulators -> 16 edges in flight per wave-iter,
// no interleaved index loads. Cross-group reduce via shfl_xor.
// ---------------------------------------------------------------------------
__global__ __launch_bounds__(256) void agg1_gemm2_kernel(const float* __restrict__ h1s,
                                                         const int* __restrict__ csr_src,
                                                         const int* __restrict__ row_start,
                                                         const float* __restrict__ dinv,
                                                         const float* __restrict__ b1,
                                                         const float* __restrict__ W2,
                                                         float* __restrict__ h2s) {
    __shared__ float W2s[F_MID * F_OUT];   // 10 KB
    int tid = threadIdx.x;
    for (int i = tid; i < F_MID * F_OUT; i += 256) W2s[i] = W2[i];
    __syncthreads();

    int node = blockIdx.x * 4 + (tid >> 6);
    int lane = tid & 63;
    int g = lane >> 4;          // edge slot group 0..3
    int l = lane & 15;          // feature quad 0..15

    int s0 = row_start[node], s1 = row_start[node + 1];
    float4 a0 = make_float4(0.f, 0.f, 0.f, 0.f);
    float4 a1 = make_float4(0.f, 0.f, 0.f, 0.f);
    float4 a2 = make_float4(0.f, 0.f, 0.f, 0.f);
    float4 a3 = make_float4(0.f, 0.f, 0.f, 0.f);

    for (int base = s0; base < s1; base += 64) {
        int cnt = s1 - base; if (cnt > 64) cnt = 64;
        int myidx = 0;
        if (lane < cnt) myidx = csr_src[base + lane];
        for (int j0 = 0; j0 < cnt; j0 += 16) {
            int jj = j0 + g;
            int i0 = __shfl(myidx, jj, 64);
            int i1 = __shfl(myidx, jj + 4, 64);
            int i2 = __shfl(myidx, jj + 8, 64);
            int i3 = __shfl(myidx, jj + 12, 64);
            if (jj < cnt)
                a0 = f4add(a0, *(const float4*)&h1s[(size_t)i0 * F_MID + l * 4]);
            if (jj + 4 < cnt)
                a1 = f4add(a1, *(const float4*)&h1s[(size_t)i1 * F_MID + l * 4]);
            if (jj + 8 < cnt)
                a2 = f4add(a2, *(const float4*)&h1s[(size_t)i2 * F_MID + l * 4]);
            if (jj + 12 < cnt)
                a3 = f4add(a3, *(const float4*)&h1s[(size_t)i3 * F_MID + l * 4]);
        }
    }
    float4 acc = f4add(f4add(a0, a1), f4add(a2, a3));
    acc = f4add(acc, f4shflxor(acc, 16));
    acc = f4add(acc, f4shflxor(acc, 32));
    // every lane's acc = full sum for features 4l..4l+3 (replicated over g)

    float dn = dinv[node];
    float4 bv = *(const float4*)&b1[l * 4];
    float4 v4;
    v4.x = fmaxf(acc.x * dn + bv.x, 0.f);
    v4.y = fmaxf(acc.y * dn + bv.y, 0.f);
    v4.z = fmaxf(acc.z * dn + bv.z, 0.f);
    v4.w = fmaxf(acc.w * dn + bv.w, 0.f);

    // gemm2: o[cl] = sum_k v[k] * W2[k][cl]; v[k] lives on lane (k>>2), comp k&3
    int cl = (lane < F_OUT) ? lane : 0;
    float o = 0.f;
#pragma unroll
    for (int kg = 0; kg < 16; kg++) {
        float vx = __shfl(v4.x, kg, 64);
        float vy = __shfl(v4.y, kg, 64);
        float vz = __shfl(v4.z, kg, 64);
        float vw = __shfl(v4.w, kg, 64);
        o = fmaf(vx, W2s[(4 * kg + 0) * F_OUT + cl], o);
        o = fmaf(vy, W2s[(4 * kg + 1) * F_OUT + cl], o);
        o = fmaf(vz, W2s[(4 * kg + 2) * F_OUT + cl], o);
        o = fmaf(vw, W2s[(4 * kg + 3) * F_OUT + cl], o);
    }
    if (lane < F_OUT) h2s[(size_t)node * F_OUT + lane] = o * dn;
}

// ---------------------------------------------------------------------------
// agg2 + bias + log_softmax: 4 nodes/block; same index-preload gather
// (16-lane groups; lanes l<10 carry float4 covering classes 4l..4l+3).
// ---------------------------------------------------------------------------
__global__ __launch_bounds__(256) void agg2_softmax_kernel(const float* __restrict__ h2s,
                                                           const int* __restrict__ csr_src,
                                                           const int* __restrict__ row_start,
                                                           const float* __restrict__ dinv,
                                                           const float* __restrict__ b2,
                                                           float* __restrict__ out) {
    int tid = threadIdx.x;
    int node = blockIdx.x * 4 + (tid >> 6);
    int lane = tid & 63;
    int g = lane >> 4;
    int l = lane & 15;
    bool act = (l < 10);        // 10 float4 = 40 classes

    int s0 = row_start[node], s1 = row_start[node + 1];
    float4 a0 = make_float4(0.f, 0.f, 0.f, 0.f);
    float4 a1 = make_float4(0.f, 0.f, 0.f, 0.f);
    float4 a2 = make_float4(0.f, 0.f, 0.f, 0.f);
    float4 a3 = make_float4(0.f, 0.f, 0.f, 0.f);

    for (int base = s0; base < s1; base += 64) {
        int cnt = s1 - base; if (cnt > 64) cnt = 64;
        int myidx = 0;
        if (lane < cnt) myidx = csr_src[base + lane];
        for (int j0 = 0; j0 < cnt; j0 += 16) {
            int jj = j0 + g;
            int i0 = __shfl(myidx, jj, 64);
            int i1 = __shfl(myidx, jj + 4, 64);
            int i2 = __shfl(myidx, jj + 8, 64);
            int i3 = __shfl(myidx, jj + 12, 64);
            if (act && jj < cnt)
                a0 = f4add(a0, *(const float4*)&h2s[(size_t)i0 * F_OUT + l * 4]);
            if (act && jj + 4 < cnt)
                a1 = f4add(a1, *(const float4*)&h2s[(size_t)i1 * F_OUT + l * 4]);
            if (act && jj + 8 < cnt)
                a2 = f4add(a2, *(const float4*)&h2s[(size_t)i2 * F_OUT + l * 4]);
            if (act && jj + 12 < cnt)
                a3 = f4add(a3, *(const float4*)&h2s[(size_t)i3 * F_OUT + l * 4]);
        }
    }
    float4 acc = f4add(f4add(a0, a1), f4add(a2, a3));
    acc = f4add(acc, f4shflxor(acc, 16));
    acc = f4add(acc, f4shflxor(acc, 32));

    float dn = dinv[node];
    float4 z4 = make_float4(0.f, 0.f, 0.f, 0.f);
    if (act) {
        float4 bv = *(const float4*)&b2[l * 4];
        z4.x = acc.x * dn + bv.x;
        z4.y = acc.y * dn + bv.y;
        z4.z = acc.z * dn + bv.z;
        z4.w = acc.w * dn + bv.w;
    }
    float m = act ? fmaxf(fmaxf(z4.x, z4.y), fmaxf(z4.z, z4.w)) : -3.4e38f;
#pragma unroll
    for (int off = 1; off < 16; off <<= 1) m = fmaxf(m, __shfl_xor(m, off, 64));
    float s = 0.f;
    if (act)
        s = __expf(z4.x - m) + __expf(z4.y - m) + __expf(z4.z - m) + __expf(z4.w - m);
#pragma unroll
    for (int off = 1; off < 16; off <<= 1) s += __shfl_xor(s, off, 64);
    float lse = m + logf(s);
    if (act) {
        float4 r = make_float4(z4.x - lse, z4.y - lse, z4.z - lse, z4.w - lse);
        *(float4*)&out[(size_t)node * F_OUT + l * 4] = r;
    }
}

// ---------------------------------------------------------------------------
extern "C" void kernel_launch(void* const* d_in, const int* in_sizes, int n_in,
                              void* d_out, int out_size, void* d_ws, size_t ws_size,
                              hipStream_t stream) {
    const float* X   = (const float*)d_in[0];
    const int*   ei  = (const int*)d_in[1];
    const float* W1  = (const float*)d_in[2];
    const float* b1  = (const float*)d_in[3];
    const float* W2  = (const float*)d_in[4];
    const float* b2  = (const float*)d_in[5];
    float* out = (float*)d_out;

    const int N = NNODES;
    const int E = in_sizes[1] / 2;      // 1,600,000
    const int TOTAL = E + N;
    const int* srcv = ei;
    const int* dstv = ei + E;

    char* p = (char*)d_ws;
    auto carve = [&](size_t bytes) {
        void* r = (void*)p;
        p += (bytes + 255) & ~(size_t)255;
        return r;
    };
    int*   cnt       = (int*)carve((size_t)N * 4);
    int*   row_start = (int*)carve((size_t)(N + 1) * 4);
    int*   cursor    = (int*)carve((size_t)N * 4);
    int*   bsum      = (int*)carve(512);
    int*   boff      = (int*)carve(512 + 4);
    int*   csr_src   = (int*)carve((size_t)TOTAL * 4);
    float* dinv      = (float*)carve((size_t)N * 4);
    unsigned short* W1T = (unsigned short*)carve((size_t)F_MID * KPAD * 2);
    float* h1s       = (float*)carve((size_t)N * F_MID * 4);
    float* h2s       = (float*)carve((size_t)N * F_OUT * 4);
    (void)ws_size; (void)n_in; (void)out_size;

    const int nb = (N + 1023) / 1024;   // 98

    hipMemsetAsync(cnt, 0, (size_t)N * 4, stream);
    hist_kernel<<<(E + 255) / 256, 256, 0, stream>>>(dstv, cnt, E);
    scan_local<<<nb, 1024, 0, stream>>>(cnt, row_start, bsum, N);
    scan_bsum<<<1, 128, 0, stream>>>(bsum, boff, nb);
    scan_apply<<<nb, 1024, 0, stream>>>(cnt, row_start, cursor, dinv, boff, N, nb);
    fill_kernel<<<(TOTAL + 255) / 256, 256, 0, stream>>>(srcv, dstv, cursor, csr_src, E, TOTAL);
    w1t_prep<<<(F_MID * KPAD + 255) / 256, 256, 0, stream>>>(W1, W1T);

    gemm1_kernel<<<(N + 127) / 128, 256, 0, stream>>>(X, W1T, dinv, h1s);
    agg1_gemm2_kernel<<<N / 4, 256, 0, stream>>>(h1s, csr_src, row_start, dinv, b1, W2, h2s);
    agg2_softmax_kernel<<<N / 4, 256, 0, stream>>>(h2s, csr_src, row_start, dinv, b2, out);
}